// Round 1
// baseline (374.217 us; speedup 1.0000x reference)
//
#include <hip/hip_runtime.h>
#include <hip/hip_bf16.h>

// Problem constants (fixed shapes)
//   B=2, L=2048, hidden=2048, H=16, KV=4, D=128, WIN=512
// Pipeline:
//   1) cast x, Wq|Wk|Wv (fused rows), Wo to bf16 in ws
//   2) qkv = x @ Wqkv^T   (bf16 MFMA GEMM, bf16 out)
//   3) RMSNorm(q,k) + RoPE + scatter to [B,heads,L,D] bf16
//   4) sliding-window flash attention (bf16 MFMA) -> attn [B*L, H*D] bf16
//   5) out = attn @ Wo^T  (bf16 MFMA GEMM, fp32 out -> d_out)

typedef unsigned short u16;
typedef __attribute__((ext_vector_type(8))) short bf16x8;
typedef __attribute__((ext_vector_type(4))) float f32x4;

__device__ __forceinline__ u16 f2b(float f) {
  __hip_bfloat16 h = __float2bfloat16(f);
  union { __hip_bfloat16 h; u16 u; } cv; cv.h = h; return cv.u;
}
__device__ __forceinline__ float b2f(u16 u) {
  union { u16 u; __hip_bfloat16 h; } cv; cv.u = u; return __bfloat162float(cv.h);
}

// ---------------- fp32 -> bf16 cast ----------------
__global__ __launch_bounds__(256) void cvt_f32_bf16(const float* __restrict__ src,
                                                    u16* __restrict__ dst, int n) {
  int i = (blockIdx.x * 256 + threadIdx.x) * 4;
  if (i >= n) return;
  float4 v = *(const float4*)(src + i);
  ushort4 o;
  o.x = f2b(v.x); o.y = f2b(v.y); o.z = f2b(v.z); o.w = f2b(v.w);
  *(ushort4*)(dst + i) = o;
}

// ---------------- bf16 GEMM: C[M,N] = A[M,K] @ B[N,K]^T ----------------
// 128x128 tile, BK=64, 256 threads = 4 waves (2x2), each wave 64x64 via 4x4
// grid of 16x16x32 MFMAs. LDS padded +8 bf16 to break bank conflicts.
template<int F32OUT>
__global__ __launch_bounds__(256) void gemm_bt(const u16* __restrict__ A,
                                               const u16* __restrict__ Bm,
                                               void* __restrict__ C,
                                               int M, int N, int K) {
  __shared__ u16 As[128][72];
  __shared__ u16 Bs[128][72];
  const int tid  = threadIdx.x;
  const int w    = tid >> 6, lane = tid & 63, quad = lane >> 4, l16 = lane & 15;
  const int wm   = w >> 1, wn = w & 1;
  const int m0   = blockIdx.y * 128, n0 = blockIdx.x * 128;

  f32x4 zero = {0.f, 0.f, 0.f, 0.f};
  f32x4 acc[4][4];
#pragma unroll
  for (int i = 0; i < 4; i++)
#pragma unroll
    for (int j = 0; j < 4; j++) acc[i][j] = zero;

  const int sr = tid >> 3;        // staging row 0..31 (+p*32)
  const int sc = (tid & 7) * 8;   // staging col (elements)

  for (int k0 = 0; k0 < K; k0 += 64) {
#pragma unroll
    for (int p = 0; p < 4; ++p) {
      int row = sr + p * 32;
      *(uint4*)&As[row][sc] = *(const uint4*)(A  + (size_t)(m0 + row) * K + k0 + sc);
      *(uint4*)&Bs[row][sc] = *(const uint4*)(Bm + (size_t)(n0 + row) * K + k0 + sc);
    }
    __syncthreads();
#pragma unroll
    for (int kk = 0; kk < 64; kk += 32) {
      bf16x8 af[4], bfr[4];
#pragma unroll
      for (int i = 0; i < 4; i++)
        af[i] = *(const bf16x8*)&As[wm * 64 + i * 16 + l16][kk + quad * 8];
#pragma unroll
      for (int j = 0; j < 4; j++)
        bfr[j] = *(const bf16x8*)&Bs[wn * 64 + j * 16 + l16][kk + quad * 8];
#pragma unroll
      for (int i = 0; i < 4; i++)
#pragma unroll
        for (int j = 0; j < 4; j++)
          acc[i][j] = __builtin_amdgcn_mfma_f32_16x16x32_bf16(af[i], bfr[j], acc[i][j], 0, 0, 0);
    }
    __syncthreads();
  }

  // epilogue: C/D layout col=lane&15, row=quad*4+reg (m89/m91-verified)
#pragma unroll
  for (int i = 0; i < 4; i++) {
#pragma unroll
    for (int r = 0; r < 4; r++) {
      int gr = m0 + wm * 64 + i * 16 + quad * 4 + r;
#pragma unroll
      for (int j = 0; j < 4; j++) {
        int gc = n0 + wn * 64 + j * 16 + l16;
        if (F32OUT) ((float*)C)[(size_t)gr * N + gc] = acc[i][j][r];
        else        ((u16*)C)[(size_t)gr * N + gc]   = f2b(acc[i][j][r]);
      }
    }
  }
}

// ---------------- RMSNorm + RoPE + layout scatter ----------------
// One wave per (row 0..4095, head 0..23). heads 0..15=q, 16..19=k, 20..23=v.
// lane handles elements d=lane and d=lane+64.
__global__ __launch_bounds__(256) void rmsrope(const u16* __restrict__ qkv,
                                               const float* __restrict__ cosT,
                                               const float* __restrict__ sinT,
                                               const float* __restrict__ qw,
                                               const float* __restrict__ kw,
                                               u16* __restrict__ qo,
                                               u16* __restrict__ ko,
                                               u16* __restrict__ vo) {
  int wid  = blockIdx.x * 4 + (threadIdx.x >> 6);
  int lane = threadIdx.x & 63;
  int r  = wid / 24;
  int hh = wid % 24;
  int b = r >> 11, l = r & 2047;
  int cb = hh < 16 ? hh * 128 : (hh < 20 ? 2048 + (hh - 16) * 128 : 2560 + (hh - 20) * 128);
  const u16* src = qkv + (size_t)r * 3072 + cb;
  float v0 = b2f(src[lane]);
  float v1 = b2f(src[lane + 64]);
  float o0, o1;
  if (hh < 20) {
    float ss = v0 * v0 + v1 * v1;
#pragma unroll
    for (int off = 1; off < 64; off <<= 1) ss += __shfl_xor(ss, off, 64);
    float inv = rsqrtf(ss * (1.0f / 128.0f) + 1e-6f);
    const float* wt = hh < 16 ? qw : kw;
    float n0 = v0 * inv * wt[lane];
    float n1 = v1 * inv * wt[lane + 64];
    float c0 = cosT[l * 128 + lane],      c1 = cosT[l * 128 + 64 + lane];
    float s0 = sinT[l * 128 + lane],      s1 = sinT[l * 128 + 64 + lane];
    o0 = n0 * c0 - n1 * s0;   // d < 64: x*cos - x[d+64]*sin
    o1 = n1 * c1 + n0 * s1;   // d >= 64: x*cos + x[d-64]*sin
  } else { o0 = v0; o1 = v1; }
  u16* dst; size_t base;
  if (hh < 16)      { dst = qo; base = ((size_t)(b * 16 + hh)        * 2048 + l) * 128; }
  else if (hh < 20) { dst = ko; base = ((size_t)(b * 4 + (hh - 16))  * 2048 + l) * 128; }
  else              { dst = vo; base = ((size_t)(b * 4 + (hh - 20))  * 2048 + l) * 128; }
  dst[base + lane]      = f2b(o0);
  dst[base + 64 + lane] = f2b(o1);
}

// ---------------- sliding-window flash attention ----------------
// Block: (q-tile 64 rows) x (h) x (b). 4 waves; wave w owns q rows w*16..w*16+15.
// K-tiles of 64 keys. K staged [key][d] (stride 136), V staged transposed
// [d][key] (stride 72), P transposed via per-wave LDS (stride 72).
__global__ __launch_bounds__(256) void flash_swa(const u16* __restrict__ Q,
                                                 const u16* __restrict__ Kg,
                                                 const u16* __restrict__ Vg,
                                                 u16* __restrict__ Og) {
  constexpr int L = 2048, D = 128;
  __shared__ u16 Ks[64][136];
  __shared__ u16 Vt[128][72];
  __shared__ u16 Ps[4][16][72];

  const int q0  = blockIdx.x * 64;
  const int h   = blockIdx.y;
  const int b   = blockIdx.z;
  const int tid = threadIdx.x;
  const int w = tid >> 6, lane = tid & 63, quad = lane >> 4, l16 = lane & 15;
  const int kvh = h >> 2;  // repeat_interleave: q head h -> kv head h/4

  const u16* Qb = Q  + (size_t)(b * 16 + h)   * L * D;
  const u16* Kb = Kg + (size_t)(b * 4 + kvh)  * L * D;
  const u16* Vb = Vg + (size_t)(b * 4 + kvh)  * L * D;

  // Q fragments (A-operand: A[m=lane&15][k=quad*8+j]), kept in regs all kernel
  bf16x8 qf[4];
  {
    int qr = q0 + w * 16 + l16;
#pragma unroll
    for (int ks = 0; ks < 4; ++ks)
      qf[ks] = *(const bf16x8*)(Qb + (size_t)qr * D + ks * 32 + quad * 8);
  }

  f32x4 zero = {0.f, 0.f, 0.f, 0.f};
  f32x4 o[8];
#pragma unroll
  for (int i = 0; i < 8; i++) o[i] = zero;
  float mrow[4], lrow[4];
#pragma unroll
  for (int r = 0; r < 4; r++) { mrow[r] = -1e30f; lrow[r] = 0.f; }

  const float scale = 0.08838834764831845f;  // 1/sqrt(128)

  int kt0   = q0 > 512 ? q0 - 512 : 0;       // both multiples of 64
  int ktend = q0 + 64 + 512; if (ktend > L) ktend = L;

  for (int kt = kt0; kt < ktend; kt += 64) {
    // ---- stage K tile [64 keys][128 d] ----
#pragma unroll
    for (int p = 0; p < 4; ++p) {
      int c = tid + p * 256;
      int row = c >> 4, c8 = (c & 15) * 8;
      *(uint4*)&Ks[row][c8] = *(const uint4*)(Kb + (size_t)(kt + row) * D + c8);
    }
    // ---- stage V transposed: Vt[d][key] ----
#pragma unroll
    for (int p = 0; p < 2; ++p) {
      int kp = tid & 31;                    // key pair (2kp, 2kp+1)
      int d0 = ((tid >> 5) << 3) + p * 64;  // 8-elem d chunk
      const u16* vp = Vb + (size_t)(kt + 2 * kp) * D + d0;
      uint4 a  = *(const uint4*)vp;
      uint4 bq = *(const uint4*)(vp + D);
      const u16* pa = (const u16*)&a;
      const u16* pb = (const u16*)&bq;
#pragma unroll
      for (int j = 0; j < 8; j++) {
        unsigned int val = (unsigned int)pa[j] | ((unsigned int)pb[j] << 16);
        *(unsigned int*)&Vt[d0 + j][2 * kp] = val;
      }
    }
    __syncthreads();

    // ---- S = Q K^T (16q x 64k per wave) ----
    f32x4 s[4];
#pragma unroll
    for (int ct = 0; ct < 4; ct++) s[ct] = zero;
#pragma unroll
    for (int ks = 0; ks < 4; ++ks) {
#pragma unroll
      for (int ct = 0; ct < 4; ++ct) {
        bf16x8 kf = *(const bf16x8*)&Ks[ct * 16 + l16][ks * 32 + quad * 8];
        s[ct] = __builtin_amdgcn_mfma_f32_16x16x32_bf16(qf[ks], kf, s[ct], 0, 0, 0);
      }
    }

    // ---- scale + window mask ----
    bool need_mask = (kt + 448 < q0) || (kt > q0 + 448);
    float sv[4][4];
#pragma unroll
    for (int ct = 0; ct < 4; ct++)
#pragma unroll
      for (int r = 0; r < 4; r++) {
        float x = s[ct][r] * scale;
        if (need_mask) {
          int ki = kt + ct * 16 + l16;
          int qi = q0 + w * 16 + quad * 4 + r;
          int dd = qi - ki; if (dd < 0) dd = -dd;
          if (dd > 512) x = -__builtin_inff();
        }
        sv[ct][r] = x;
      }

    // ---- online softmax (rows quad*4+r live in 16-lane group) ----
    float mt[4];
#pragma unroll
    for (int r = 0; r < 4; r++) {
      float v = fmaxf(fmaxf(sv[0][r], sv[1][r]), fmaxf(sv[2][r], sv[3][r]));
#pragma unroll
      for (int off = 1; off < 16; off <<= 1) v = fmaxf(v, __shfl_xor(v, off, 16));
      mt[r] = v;
    }
    float alpha[4], mnew[4];
#pragma unroll
    for (int r = 0; r < 4; r++) {
      mnew[r]  = fmaxf(mrow[r], mt[r]);     // >= -1e30, never -inf
      alpha[r] = __expf(mrow[r] - mnew[r]);
    }
    float psum[4] = {0.f, 0.f, 0.f, 0.f};
#pragma unroll
    for (int ct = 0; ct < 4; ct++)
#pragma unroll
      for (int r = 0; r < 4; r++) {
        float p = __expf(sv[ct][r] - mnew[r]);  // masked: exp(-inf)=0
        psum[r] += p;
        Ps[w][quad * 4 + r][ct * 16 + l16] = f2b(p);
      }
#pragma unroll
    for (int r = 0; r < 4; r++) {
      float v = psum[r];
#pragma unroll
      for (int off = 1; off < 16; off <<= 1) v += __shfl_xor(v, off, 16);
      lrow[r] = lrow[r] * alpha[r] + v;
      mrow[r] = mnew[r];
    }
#pragma unroll
    for (int dt = 0; dt < 8; dt++)
#pragma unroll
      for (int r = 0; r < 4; r++) o[dt][r] *= alpha[r];

    // ---- O += P V (P via LDS round-trip into A-layout) ----
    bf16x8 pf[2];
#pragma unroll
    for (int ks2 = 0; ks2 < 2; ++ks2)
      pf[ks2] = *(const bf16x8*)&Ps[w][l16][ks2 * 32 + quad * 8];
#pragma unroll
    for (int dt = 0; dt < 8; ++dt) {
#pragma unroll
      for (int ks2 = 0; ks2 < 2; ++ks2) {
        bf16x8 vf = *(const bf16x8*)&Vt[dt * 16 + l16][ks2 * 32 + quad * 8];
        o[dt] = __builtin_amdgcn_mfma_f32_16x16x32_bf16(pf[ks2], vf, o[dt], 0, 0, 0);
      }
    }
    __syncthreads();
  }

  // ---- epilogue: divide by l, store [B*L, H*D] bf16 ----
#pragma unroll
  for (int r = 0; r < 4; r++) {
    float inv = 1.0f / lrow[r];
    int qr = q0 + w * 16 + quad * 4 + r;
    size_t base = ((size_t)(b * L + qr)) * 2048 + h * 128;
#pragma unroll
    for (int dt = 0; dt < 8; dt++)
      Og[base + dt * 16 + l16] = f2b(o[dt][r] * inv);
  }
}

// ---------------- launch ----------------
extern "C" void kernel_launch(void* const* d_in, const int* in_sizes, int n_in,
                              void* d_out, int out_size, void* d_ws, size_t ws_size,
                              hipStream_t stream) {
  const float* x    = (const float*)d_in[0];
  const float* cosT = (const float*)d_in[1];
  const float* sinT = (const float*)d_in[2];
  const float* Wq   = (const float*)d_in[3];
  const float* Wk   = (const float*)d_in[4];
  const float* Wv   = (const float*)d_in[5];
  const float* Wo   = (const float*)d_in[6];
  const float* qw   = (const float*)d_in[7];
  const float* kw   = (const float*)d_in[8];

  char* ws = (char*)d_ws;
  // ws layout (bytes); attn_bf reuses x_bf region (x dead after gemm1)
  u16* x_bf    = (u16*)(ws + 0);          // 16 MB  [4096,2048]
  u16* wqkv_bf = (u16*)(ws + 16777216);   // 12 MB  [3072,2048]
  u16* wo_bf   = (u16*)(ws + 29360128);   //  8 MB  [2048,2048]
  u16* qkv_bf  = (u16*)(ws + 37748736);   // 24 MB  [4096,3072]
  u16* q_bf    = (u16*)(ws + 62914560);   // 16 MB  [2,16,2048,128]
  u16* k_bf    = (u16*)(ws + 79691776);   //  4 MB  [2,4,2048,128]
  u16* v_bf    = (u16*)(ws + 83886080);   //  4 MB  [2,4,2048,128]
  u16* attn_bf = x_bf;                    // 16 MB  [4096,2048]

  cvt_f32_bf16<<<8192, 256, 0, stream>>>(x,  x_bf,    8388608);
  cvt_f32_bf16<<<4096, 256, 0, stream>>>(Wq, wqkv_bf, 4194304);
  cvt_f32_bf16<<<1024, 256, 0, stream>>>(Wk, wqkv_bf + 2048 * 2048,              1048576);
  cvt_f32_bf16<<<1024, 256, 0, stream>>>(Wv, wqkv_bf + 2048 * 2048 + 512 * 2048, 1048576);
  cvt_f32_bf16<<<4096, 256, 0, stream>>>(Wo, wo_bf,   4194304);

  gemm_bt<0><<<dim3(24, 32), 256, 0, stream>>>(x_bf, wqkv_bf, qkv_bf, 4096, 3072, 2048);
  rmsrope<<<24576, 256, 0, stream>>>(qkv_bf, cosT, sinT, qw, kw, q_bf, k_bf, v_bf);
  flash_swa<<<dim3(32, 16, 2), 256, 0, stream>>>(q_bf, k_bf, v_bf, attn_bf);
  gemm_bt<1><<<dim3(16, 32), 256, 0, stream>>>(attn_bf, wo_bf, d_out, 4096, 2048, 2048);
}